// Round 15
// baseline (522.611 us; speedup 1.0000x reference)
//
#include <hip/hip_runtime.h>
#include <hip/hip_bf16.h>

#define B_ 32
#define P_ 512
#define Q_ 64
#define E_ 300
#define KP 320          // E padded to multiple of 32 for MFMA K-steps
#define H_ 256
#define HH_ 128
#define NEG (-1e7f)
#define BP (B_*P_)
#define BQ (B_*Q_)

typedef __attribute__((ext_vector_type(8))) short bf16x8;
typedef __attribute__((ext_vector_type(4))) float f32x4;
typedef _Float16 half2v __attribute__((ext_vector_type(2)));
typedef unsigned int u32;

// ---- DPP cross-lane helpers: xor1/xor2 as quad_perm (VALU, no LDS pipe) ----
__device__ __forceinline__ float dpp_x1(float x) {
    return __builtin_bit_cast(float,
        __builtin_amdgcn_mov_dpp(__builtin_bit_cast(int, x), 0xB1, 0xF, 0xF, true));
}
__device__ __forceinline__ float dpp_x2(float x) {
    return __builtin_bit_cast(float,
        __builtin_amdgcn_mov_dpp(__builtin_bit_cast(int, x), 0x4E, 0xF, 0xF, true));
}
__device__ __forceinline__ float qsum(float x) { x += dpp_x1(x); x += dpp_x2(x); return x; }
__device__ __forceinline__ float wsum(float x) {
    x = qsum(x);
    x += __shfl_xor(x, 4);  x += __shfl_xor(x, 8);
    x += __shfl_xor(x, 16); x += __shfl_xor(x, 32);
    return x;
}
__device__ __forceinline__ float wmax(float x) {
    x = fmaxf(x, dpp_x1(x)); x = fmaxf(x, dpp_x2(x));
    x = fmaxf(x, __shfl_xor(x, 4));  x = fmaxf(x, __shfl_xor(x, 8));
    x = fmaxf(x, __shfl_xor(x, 16)); x = fmaxf(x, __shfl_xor(x, 32));
    return x;
}

// ---- static device workspace (fully rewritten every call) ----
__device__ __hip_bfloat16 g_wp[768][KP];     // combined passage wih (bf16, K-padded)
__device__ __hip_bfloat16 g_wq[768][KP];     // combined question wih
__device__ float g_biasp[768];               // bih (+ bhh for r,z gates)
__device__ float g_biasq[768];
__device__ float g_biasn[4][HH_];            // bhh n-gate bias per weight set
__device__ uint4 g_whhw[4*512*12];           // [widx][tid=(j,q)][gate][4] f16-packed
__device__ _Float16 g_xtp[2L*P_*B_*384];     // passage x-proj, [dir][t][b][384] f16
__device__ _Float16 g_xtq[2L*Q_*B_*384];     // question x-proj (masked z cols = +inf)
__device__ float g_penc[BP*H_];              // BiGRU passage encodings (f32)
__device__ float g_qenc[BQ*H_];              // BiGRU question encodings

struct PrepArgs { const float* wih[4]; const float* whh[4]; const float* bih[4]; const float* bhh[4]; };

// ---------------- combined weight repack: wih->bf16 + bias fold + whh->f16 frags ----------------
__global__ __launch_bounds__(512) void k_prep(PrepArgs pa) {
    int blk = blockIdx.x;
    int tid = threadIdx.x;
    if (blk < 192) {                    // wih repack: 8 rows per block
        int r = blk * 8 + (tid >> 6);   // 0..1535
        int lane = tid & 63;
        int pq = r / 768, col = r % 768;
        int dir = col / 384, within = col % 384, gate = within / 128;
        int idx = pq * 2 + dir;         // {p_f,p_b,q_f,q_b}
        const float* wsrc = pa.wih[idx] + within * E_;
        __hip_bfloat16* dst = pq ? g_wq[col] : g_wp[col];
        for (int c = lane; c < KP; c += 64)
            dst[c] = __float2bfloat16(c < E_ ? wsrc[c] : 0.f);
        if (lane == 0) {
            float bsum = pa.bih[idx][within] + (gate < 2 ? pa.bhh[idx][within] : 0.f);
            (pq ? g_biasq : g_biasp)[col] = bsum;
            if (within >= 256) g_biasn[idx][within - 256] = pa.bhh[idx][within];
        }
    } else {                            // whh -> per-thread f16-packed quarter-rows
        int widx = blk - 192;           // 0..3
        const float* whh = pa.whh[widx];
        int j = tid >> 2, q = tid & 3;
        uint4* dst = g_whhw + ((long)widx * 512 + tid) * 12;
        for (int g = 0; g < 3; g++)
            for (int i = 0; i < 4; i++) {
                const float* src = whh + (long)(g * 128 + j) * HH_ + q * 32 + i * 8;
                u32 p[4];
                #pragma unroll
                for (int e = 0; e < 4; e++) {
                    half2v hp;
                    hp[0] = (_Float16)src[2 * e];
                    hp[1] = (_Float16)src[2 * e + 1];
                    p[e] = __builtin_bit_cast(u32, hp);
                }
                dst[g * 4 + i] = make_uint4(p[0], p[1], p[2], p[3]);
            }
    }
}

// ---------------- GEMM with fused embedding gather + f16 x-write + z-poison ----------------
__global__ __launch_bounds__(256) void k_gemm(const int* pass, const int* ques, const float* emb) {
    int bx = blockIdx.x;
    int isQ = bx >= 128;
    int mblk = isQ ? bx - 128 : bx;
    const __hip_bfloat16* Bw = isQ ? &g_wq[0][0] : &g_wp[0][0];
    const float* bias = isQ ? g_biasq : g_biasp;
    _Float16* Xt = isQ ? g_xtq : g_xtp;
    const int* tsrc = isQ ? ques : pass;
    const int T = isQ ? Q_ : P_;
    __shared__ __hip_bfloat16 As[128][40];
    __shared__ __hip_bfloat16 Bs[128][40];
    __shared__ int toks[128];
    int m0 = mblk * 128, n0 = blockIdx.y * 128;
    int tid = threadIdx.x, lane = tid & 63, w = tid >> 6;
    int wm = (w & 1) * 64, wn = (w >> 1) * 64;
    if (tid < 128) {                    // token table for this M-tile (t-major rows)
        int m = m0 + tid;
        int t = m >> 5, bb = m & 31;
        toks[tid] = tsrc[bb * T + t];
    }
    f32x4 acc[4][4] = {};
    int lr = tid >> 1, lc = (tid & 1) * 16;
    __syncthreads();                    // toks visible
    long arow = (long)toks[lr] * E_;
    for (int kt = 0; kt < KP; kt += 32) {
        int c0 = kt + lc;
        const float* er = emb + arow + c0;
        __hip_bfloat16 a16[16];
        if (c0 + 16 <= E_) {            // fast path: 4x float4 (16B-aligned: 300*4B = 75*16B)
            #pragma unroll
            for (int i4 = 0; i4 < 4; i4++) {
                float4 v = *(const float4*)(er + i4 * 4);
                a16[i4*4]   = __float2bfloat16(v.x);
                a16[i4*4+1] = __float2bfloat16(v.y);
                a16[i4*4+2] = __float2bfloat16(v.z);
                a16[i4*4+3] = __float2bfloat16(v.w);
            }
        } else {                        // tail: guarded scalar
            #pragma unroll
            for (int i = 0; i < 16; i++) {
                int c = c0 + i;
                a16[i] = __float2bfloat16((c < E_) ? er[i] : 0.f);
            }
        }
        *(bf16x8*)&As[lr][lc]   = *(bf16x8*)&a16[0];
        *(bf16x8*)&As[lr][lc+8] = *(bf16x8*)&a16[8];
        *(bf16x8*)&Bs[lr][lc]   = *(const bf16x8*)&Bw[(n0 + lr) * KP + kt + lc];
        *(bf16x8*)&Bs[lr][lc+8] = *(const bf16x8*)&Bw[(n0 + lr) * KP + kt + lc + 8];
        __syncthreads();
        int kb = (lane >> 4) * 8, l15 = lane & 15;
        bf16x8 af[4], bfr[4];
        #pragma unroll
        for (int i = 0; i < 4; i++) af[i]  = *(bf16x8*)&As[wm + i*16 + l15][kb];
        #pragma unroll
        for (int j = 0; j < 4; j++) bfr[j] = *(bf16x8*)&Bs[wn + j*16 + l15][kb];
        #pragma unroll
        for (int i = 0; i < 4; i++)
            #pragma unroll
            for (int j = 0; j < 4; j++)
                acc[i][j] = __builtin_amdgcn_mfma_f32_16x16x32_bf16(af[i], bfr[j], acc[i][j], 0, 0, 0);
        __syncthreads();
    }
    int l15 = lane & 15, lr4 = (lane >> 4) * 4;
    const _Float16 inf16 = __builtin_bit_cast(_Float16, (unsigned short)0x7C00);
    #pragma unroll
    for (int jj = 0; jj < 4; jj++) {
        int n = n0 + wn + jj * 16 + l15;
        float bn = bias[n];
        int dirn = n >= 384;
        int col = n - dirn * 384;
        int zcol = (col >= 128) & (col < 256);
        _Float16* Cx = Xt + (long)dirn * T * B_ * 384;
        #pragma unroll
        for (int i = 0; i < 4; i++) {
            int mb = m0 + wm + i * 16 + lr4;     // T-major rows: t = m>>5, b = m&31
            int t = mb >> 5, bb = mb & 31;
            int lrow = wm + i * 16 + lr4;
            #pragma unroll
            for (int q = 0; q < 4; q++) {
                _Float16 v = (_Float16)(acc[i][jj][q] + bn);
                if (zcol && toks[lrow + q] == 0) v = inf16;   // freeze h at masked steps
                Cx[((long)t * B_ + bb + q) * 384 + col] = v;
            }
        }
    }
}

// ---------------- GRU recurrence: 4-way K-split, DPP quad-reduce ----------------
#define D1(A, WU, HU) A = __builtin_amdgcn_fdot2( \
    __builtin_bit_cast(half2v, (WU)), __builtin_bit_cast(half2v, (HU)), A, false);
#define D4(A, W, H) D1(A,(W).x,(H).x) D1(A,(W).y,(H).y) D1(A,(W).z,(H).z) D1(A,(W).w,(H).w)

__global__ __launch_bounds__(512, 1) void k_gru() {
    int blk = blockIdx.x;               // [isQ][dir][b]
    int isQ = blk >> 6, loc = blk & 63, dir = loc >> 5, b = loc & 31;
    const int T = isQ ? Q_ : P_;
    const _Float16* xt = (isQ ? g_xtq : g_xtp) + (long)dir * T * B_ * 384;
    float* outp = isQ ? g_qenc : g_penc;
    int widx = isQ * 2 + dir;
    int tid = threadIdx.x;
    int j = tid >> 2, q = tid & 3;      // col 0..127, k-quarter 0..3
    const uint4* wp = g_whhw + ((long)widx * 512 + tid) * 12;
    uint4 w00 = wp[0], w01 = wp[1], w02 = wp[2],  w03 = wp[3];
    uint4 w10 = wp[4], w11 = wp[5], w12 = wp[6],  w13 = wp[7];
    uint4 w20 = wp[8], w21 = wp[9], w22 = wp[10], w23 = wp[11];
    float bnnq = (q == 0) ? g_biasn[widx][j] : 0.f;   // folded into pre-reduce partial
    __shared__ uint hbuf[2][64];        // h as packed f16 (256B), double-buffered
    int t0 = dir ? T - 1 : 0;
    int sdt = dir ? -(B_ * 384) : (B_ * 384);
    int sdo = dir ? -H_ : H_;
    int off = (t0 * B_ + b) * 384 + j;
    int ooff = (b * T + t0) * H_ + dir * HH_ + j;
    // xr/xz only needed on q==0 lanes (folded into partials pre-reduce); xn on all
    float xr = 0.f, xz = 0.f;
    if (q == 0) { xr = (float)xt[off]; xz = (float)xt[off + 128]; }
    float xn = (float)xt[off + 256];
    uint4 z4 = {0u, 0u, 0u, 0u};
    uint4 h0 = z4, h1 = z4, h2 = z4, h3 = z4;
    float hold = 0.f;
    for (int st = 0; st < T; st++) {
        int offn = off + ((st + 1 < T) ? sdt : 0);
        float nxr = 0.f, nxz = 0.f;
        if (q == 0) { nxr = (float)xt[offn]; nxz = (float)xt[offn + 128]; }
        float nxn = (float)xt[offn + 256];
        float ar0 = 0.f, ar1 = 0.f, az0 = 0.f, az1 = 0.f, an0 = 0.f, an1 = 0.f;
        D4(ar0, w00, h0) D4(ar1, w01, h1) D4(ar0, w02, h2) D4(ar1, w03, h3)
        D4(az0, w10, h0) D4(az1, w11, h1) D4(az0, w12, h2) D4(az1, w13, h3)
        D4(an0, w20, h0) D4(an1, w21, h1) D4(an0, w22, h2) D4(an1, w23, h3)
        // quad reduce via DPP (VALU); x/bias pre-folded at q==0 so post-reduce chain is minimal
        float ar = qsum(ar0 + ar1 + xr);
        float az = qsum(az0 + az1 + xz);
        float an = qsum(an0 + an1 + bnnq);
        // gates (masked steps: xz=+inf -> az=+inf -> z=1 -> h frozen exactly)
        float rg = __builtin_amdgcn_rcpf(1.f + __expf(-ar));
        float zg = __builtin_amdgcn_rcpf(1.f + __expf(-az));
        float ta = __builtin_amdgcn_fmed3f(fmaf(rg, an, xn), -15.f, 15.f);
        float e2 = __expf(2.f * ta);
        float th = fmaf(-2.f, __builtin_amdgcn_rcpf(e2 + 1.f), 1.f);
        float hv = fmaf(zg, hold - th, th);
        hold = hv;
        if (q == 0) {
            ((_Float16*)hbuf[st & 1])[j] = (_Float16)hv; // 2B h write (issue first)
            outp[ooff] = hv;                             // fire-and-forget store
        }
        asm volatile("s_waitcnt lgkmcnt(0)\n\ts_barrier" ::: "memory");
        const uint4* hb = (const uint4*)hbuf[st & 1] + q * 4;
        h0 = hb[0]; h1 = hb[1]; h2 = hb[2]; h3 = hb[3];
        off = offn; ooff += sdo;
        xr = nxr; xz = nxz; xn = nxn;
    }
}

// ---------------- fused attention + output heads: wave-per-row, barrier-free ----------------
#define QH 288
__global__ __launch_bounds__(256) void k_attn(const int* pass, const int* ques,
        const float* attn_w, const float* attn_b, const float* start_w,
        const float* start_b, const float* end_w, const float* end_b, float* out) {
    __shared__ _Float16 qsh[64][QH];    // 36,864 B
    __shared__ uint pw3u[4][128];       // per-wave pw3 as f16 pairs
    __shared__ _Float16 w2h[256];
    int b = blockIdx.x >> 4, pblk = blockIdx.x & 15;
    int tid = threadIdx.x, lane = tid & 63, wid = tid >> 6;
    {   // stage qenc (f32 -> f16)
        int q = tid >> 2, hb = (tid & 3) * 64;
        const float* src = g_qenc + ((long)(b * Q_ + q)) * H_ + hb;
        #pragma unroll
        for (int i = 0; i < 16; i++) {
            float4 v = *(const float4*)(src + i * 4);
            half2v a, c;
            a[0] = (_Float16)v.x; a[1] = (_Float16)v.y;
            c[0] = (_Float16)v.z; c[1] = (_Float16)v.w;
            uint2 pk = { __builtin_bit_cast(u32, a), __builtin_bit_cast(u32, c) };
            *(uint2*)&qsh[q][hb + i * 4] = pk;
        }
        if (tid < 128) {
            half2v a;
            a[0] = (_Float16)attn_w[256 + 2 * tid];
            a[1] = (_Float16)attn_w[256 + 2 * tid + 1];
            *(uint*)&w2h[2 * tid] = __builtin_bit_cast(u32, a);
        }
    }
    __syncthreads();                    // only barrier in the kernel
    int qm = ques[b * Q_ + lane] != 0;
    float s2;
    {
        float a0 = 0.f, a1 = 0.f;
        const uint4* qrow = (const uint4*)&qsh[lane][0];
        const uint4* wrow = (const uint4*)w2h;
        #pragma unroll
        for (int i = 0; i < 32; i++) {
            uint4 qv = qrow[i]; uint4 wv = wrow[i];
            D1(a0, qv.x, wv.x) D1(a1, qv.y, wv.y) D1(a0, qv.z, wv.z) D1(a1, qv.w, wv.w)
        }
        s2 = a0 + a1;
    }
    float4 w1 = *(const float4*)(attn_w + 4 * lane);
    float4 w3 = *(const float4*)(attn_w + 512 + 4 * lane);
    float4 sA = *(const float4*)(start_w + 4 * lane);
    float4 sB = *(const float4*)(start_w + 256 + 4 * lane);
    float4 sC = *(const float4*)(start_w + 512 + 4 * lane);
    float4 eA = *(const float4*)(end_w + 4 * lane);
    float4 eB = *(const float4*)(end_w + 256 + 4 * lane);
    float4 eC = *(const float4*)(end_w + 512 + 4 * lane);
    float ab = attn_b[0], sb = start_b[0], ebv = end_b[0];
    uint* mypw = pw3u[wid];
    const uint4* pwrow = (const uint4*)mypw;
    for (int r = 0; r < 8; r++) {
        int p = pblk * 32 + wid * 8 + r;
        long prow = (long)(b * P_ + p);
        int ptok = pass[prow];          // prefetched, used at the end
        float4 pv = *(const float4*)(g_penc + prow * H_ + 4 * lane);
        float s1p = wsum(pv.x * w1.x + pv.y * w1.y + pv.z * w1.z + pv.w * w1.w);
        half2v h01, h23;
        h01[0] = (_Float16)(pv.x * w3.x); h01[1] = (_Float16)(pv.y * w3.y);
        h23[0] = (_Float16)(pv.z * w3.z); h23[1] = (_Float16)(pv.w * w3.w);
        mypw[2 * lane]     = __builtin_bit_cast(u32, h01);
        mypw[2 * lane + 1] = __builtin_bit_cast(u32, h23);
        asm volatile("s_waitcnt lgkmcnt(0)" ::: "memory");  // same-wave LDS visibility
        float c0 = 0.f, c1 = 0.f;
        const uint4* qrow = (const uint4*)&qsh[lane][0];
        #pragma unroll
        for (int i = 0; i < 32; i++) {
            uint4 qv = qrow[i]; uint4 wv = pwrow[i];
            D1(c0, qv.x, wv.x) D1(c1, qv.y, wv.y) D1(c0, qv.z, wv.z) D1(c1, qv.w, wv.w)
        }
        float logit = qm ? (s1p + s2 + c0 + c1 + ab) : NEG;
        float m = wmax(logit);
        float e = __expf(logit - m);
        float ss = wsum(e);
        float prob = e / ss;
        // attw for own h = 4*lane..4*lane+3 (packed f16 accum)
        half2v aw01 = {(_Float16)0.f, (_Float16)0.f}, aw23 = aw01;
        #pragma unroll 8
        for (int q2 = 0; q2 < 64; q2++) {
            float pq = __shfl(prob, q2);
            half2v ph; ph[0] = (_Float16)pq; ph[1] = ph[0];
            uint2 qv = *(const uint2*)&qsh[q2][4 * lane];
            aw01 += __builtin_bit_cast(half2v, qv.x) * ph;
            aw23 += __builtin_bit_cast(half2v, qv.y) * ph;
        }
        float a0 = (float)aw01[0], a1 = (float)aw01[1];
        float a2 = (float)aw23[0], a3 = (float)aw23[1];
        float spv = pv.x * sA.x + a0 * sB.x + pv.x * a0 * sC.x
                  + pv.y * sA.y + a1 * sB.y + pv.y * a1 * sC.y
                  + pv.z * sA.z + a2 * sB.z + pv.z * a2 * sC.z
                  + pv.w * sA.w + a3 * sB.w + pv.w * a3 * sC.w;
        float epv = pv.x * eA.x + a0 * eB.x + pv.x * a0 * eC.x
                  + pv.y * eA.y + a1 * eB.y + pv.y * a1 * eC.y
                  + pv.z * eA.z + a2 * eB.z + pv.z * a2 * eC.z
                  + pv.w * eA.w + a3 * eB.w + pv.w * a3 * eC.w;
        spv = wsum(spv);
        epv = wsum(epv);
        if (lane == 0) {
            int pm = (ptok != 0);
            out[prow]      = pm ? (spv + sb)  : NEG;
            out[BP + prow] = pm ? (epv + ebv) : NEG;
        }
    }
}

// ---------------- log_softmax over P per (batch, start/end) ----------------
__global__ __launch_bounds__(256) void k_lsm(float* out) {
    int b = blockIdx.x >> 1, which = blockIdx.x & 1;
    const float* src = out + which * BP + b * P_;
    int tid = threadIdx.x;
    float v0 = src[tid], v1 = src[tid + 256];
    __shared__ float red[4];
    float m = wmax(fmaxf(v0, v1));
    if ((tid & 63) == 0) red[tid >> 6] = m;
    __syncthreads();
    m = fmaxf(fmaxf(red[0], red[1]), fmaxf(red[2], red[3]));
    __syncthreads();
    float ss = wsum(__expf(v0 - m) + __expf(v1 - m));
    if ((tid & 63) == 0) red[tid >> 6] = ss;
    __syncthreads();
    float lse = m + logf(red[0] + red[1] + red[2] + red[3]);
    float* dst = out + (2 + which) * BP + b * P_;
    dst[tid] = v0 - lse;
    dst[tid + 256] = v1 - lse;
}

extern "C" void kernel_launch(void* const* d_in, const int* in_sizes, int n_in,
                              void* d_out, int out_size, void* d_ws, size_t ws_size,
                              hipStream_t stream) {
    const int* pass = (const int*)d_in[0];
    const int* ques = (const int*)d_in[1];
    const float* emb = (const float*)d_in[2];
    PrepArgs pa;
    const int base[4] = {3, 7, 11, 15};   // p_f, p_b, q_f, q_b blocks of 4 inputs
    for (int i = 0; i < 4; i++) {
        pa.wih[i] = (const float*)d_in[base[i] + 0];
        pa.whh[i] = (const float*)d_in[base[i] + 1];
        pa.bih[i] = (const float*)d_in[base[i] + 2];
        pa.bhh[i] = (const float*)d_in[base[i] + 3];
    }
    const float* attn_w  = (const float*)d_in[19];
    const float* attn_b  = (const float*)d_in[20];
    const float* start_w = (const float*)d_in[21];
    const float* start_b = (const float*)d_in[22];
    const float* end_w   = (const float*)d_in[23];
    const float* end_b   = (const float*)d_in[24];
    float* out = (float*)d_out;

    k_prep <<<dim3(196), dim3(512), 0, stream>>>(pa);
    k_gemm <<<dim3(144, 6), dim3(256), 0, stream>>>(pass, ques, emb);
    k_gru  <<<dim3(128), dim3(512), 0, stream>>>();
    k_attn <<<dim3(B_ * 16), dim3(256), 0, stream>>>(pass, ques, attn_w, attn_b,
                                                     start_w, start_b, end_w, end_b, out);
    k_lsm  <<<dim3(64), dim3(256), 0, stream>>>(out);
}

// Round 16
// 393.165 us; speedup vs baseline: 1.3292x; 1.3292x over previous
//
#include <hip/hip_runtime.h>
#include <hip/hip_bf16.h>

#define B_ 32
#define P_ 512
#define Q_ 64
#define E_ 300
#define KP 320          // E padded to multiple of 32 for MFMA K-steps
#define H_ 256
#define HH_ 128
#define NEG (-1e7f)
#define BP (B_*P_)
#define BQ (B_*Q_)

typedef __attribute__((ext_vector_type(8))) short bf16x8;
typedef __attribute__((ext_vector_type(4))) float f32x4;
typedef _Float16 half2v __attribute__((ext_vector_type(2)));
typedef unsigned int u32;

// ---- wave-reduce helpers (pure shfl_xor / ds_bpermute — r14 semantics) ----
__device__ __forceinline__ float wsum(float x) {
    #pragma unroll
    for (int s = 1; s < 64; s <<= 1) x += __shfl_xor(x, s);
    return x;
}
__device__ __forceinline__ float wmax(float x) {
    #pragma unroll
    for (int s = 1; s < 64; s <<= 1) x = fmaxf(x, __shfl_xor(x, s));
    return x;
}

// ---- static device workspace (fully rewritten every call) ----
__device__ __hip_bfloat16 g_wp[768][KP];     // combined passage wih (bf16, K-padded)
__device__ __hip_bfloat16 g_wq[768][KP];     // combined question wih
__device__ float g_biasp[768];               // bih (+ bhh for r,z gates)
__device__ float g_biasq[768];
__device__ float g_biasn[4][HH_];            // bhh n-gate bias per weight set
__device__ uint4 g_whhw[4*512*12];           // [widx][tid=(j,q)][gate][4] f16-packed
__device__ _Float16 g_xtp[2L*P_*B_*384];     // passage x-proj, [dir][t][b][384] f16
__device__ _Float16 g_xtq[2L*Q_*B_*384];     // question x-proj (masked z cols = +inf)
__device__ float g_penc[BP*H_];              // BiGRU passage encodings (f32)
__device__ float g_qenc[BQ*H_];              // BiGRU question encodings

struct PrepArgs { const float* wih[4]; const float* whh[4]; const float* bih[4]; const float* bhh[4]; };

// ---------------- combined weight repack: wih->bf16 + bias fold + whh->f16 frags ----------------
__global__ __launch_bounds__(512) void k_prep(PrepArgs pa) {
    int blk = blockIdx.x;
    int tid = threadIdx.x;
    if (blk < 192) {                    // wih repack: 8 rows per block
        int r = blk * 8 + (tid >> 6);   // 0..1535
        int lane = tid & 63;
        int pq = r / 768, col = r % 768;
        int dir = col / 384, within = col % 384, gate = within / 128;
        int idx = pq * 2 + dir;         // {p_f,p_b,q_f,q_b}
        const float* wsrc = pa.wih[idx] + within * E_;
        __hip_bfloat16* dst = pq ? g_wq[col] : g_wp[col];
        for (int c = lane; c < KP; c += 64)
            dst[c] = __float2bfloat16(c < E_ ? wsrc[c] : 0.f);
        if (lane == 0) {
            float bsum = pa.bih[idx][within] + (gate < 2 ? pa.bhh[idx][within] : 0.f);
            (pq ? g_biasq : g_biasp)[col] = bsum;
            if (within >= 256) g_biasn[idx][within - 256] = pa.bhh[idx][within];
        }
    } else {                            // whh -> per-thread f16-packed quarter-rows
        int widx = blk - 192;           // 0..3
        const float* whh = pa.whh[widx];
        int j = tid >> 2, q = tid & 3;
        uint4* dst = g_whhw + ((long)widx * 512 + tid) * 12;
        for (int g = 0; g < 3; g++)
            for (int i = 0; i < 4; i++) {
                const float* src = whh + (long)(g * 128 + j) * HH_ + q * 32 + i * 8;
                u32 p[4];
                #pragma unroll
                for (int e = 0; e < 4; e++) {
                    half2v hp;
                    hp[0] = (_Float16)src[2 * e];
                    hp[1] = (_Float16)src[2 * e + 1];
                    p[e] = __builtin_bit_cast(u32, hp);
                }
                dst[g * 4 + i] = make_uint4(p[0], p[1], p[2], p[3]);
            }
    }
}

// ---------------- GEMM with fused embedding gather + f16 x-write + z-poison ----------------
__global__ __launch_bounds__(256) void k_gemm(const int* pass, const int* ques, const float* emb) {
    int bx = blockIdx.x;
    int isQ = bx >= 128;
    int mblk = isQ ? bx - 128 : bx;
    const __hip_bfloat16* Bw = isQ ? &g_wq[0][0] : &g_wp[0][0];
    const float* bias = isQ ? g_biasq : g_biasp;
    _Float16* Xt = isQ ? g_xtq : g_xtp;
    const int* tsrc = isQ ? ques : pass;
    const int T = isQ ? Q_ : P_;
    __shared__ __hip_bfloat16 As[128][40];
    __shared__ __hip_bfloat16 Bs[128][40];
    __shared__ int toks[128];
    int m0 = mblk * 128, n0 = blockIdx.y * 128;
    int tid = threadIdx.x, lane = tid & 63, w = tid >> 6;
    int wm = (w & 1) * 64, wn = (w >> 1) * 64;
    if (tid < 128) {                    // token table for this M-tile (t-major rows)
        int m = m0 + tid;
        int t = m >> 5, bb = m & 31;
        toks[tid] = tsrc[bb * T + t];
    }
    f32x4 acc[4][4] = {};
    int lr = tid >> 1, lc = (tid & 1) * 16;
    __syncthreads();                    // toks visible
    long arow = (long)toks[lr] * E_;
    for (int kt = 0; kt < KP; kt += 32) {
        int c0 = kt + lc;
        const float* er = emb + arow + c0;
        __hip_bfloat16 a16[16];
        if (c0 + 16 <= E_) {            // fast path: 4x float4 (16B-aligned: 300*4B = 75*16B)
            #pragma unroll
            for (int i4 = 0; i4 < 4; i4++) {
                float4 v = *(const float4*)(er + i4 * 4);
                a16[i4*4]   = __float2bfloat16(v.x);
                a16[i4*4+1] = __float2bfloat16(v.y);
                a16[i4*4+2] = __float2bfloat16(v.z);
                a16[i4*4+3] = __float2bfloat16(v.w);
            }
        } else {                        // tail: guarded scalar
            #pragma unroll
            for (int i = 0; i < 16; i++) {
                int c = c0 + i;
                a16[i] = __float2bfloat16((c < E_) ? er[i] : 0.f);
            }
        }
        *(bf16x8*)&As[lr][lc]   = *(bf16x8*)&a16[0];
        *(bf16x8*)&As[lr][lc+8] = *(bf16x8*)&a16[8];
        *(bf16x8*)&Bs[lr][lc]   = *(const bf16x8*)&Bw[(n0 + lr) * KP + kt + lc];
        *(bf16x8*)&Bs[lr][lc+8] = *(const bf16x8*)&Bw[(n0 + lr) * KP + kt + lc + 8];
        __syncthreads();
        int kb = (lane >> 4) * 8, l15 = lane & 15;
        bf16x8 af[4], bfr[4];
        #pragma unroll
        for (int i = 0; i < 4; i++) af[i]  = *(bf16x8*)&As[wm + i*16 + l15][kb];
        #pragma unroll
        for (int j = 0; j < 4; j++) bfr[j] = *(bf16x8*)&Bs[wn + j*16 + l15][kb];
        #pragma unroll
        for (int i = 0; i < 4; i++)
            #pragma unroll
            for (int j = 0; j < 4; j++)
                acc[i][j] = __builtin_amdgcn_mfma_f32_16x16x32_bf16(af[i], bfr[j], acc[i][j], 0, 0, 0);
        __syncthreads();
    }
    int l15 = lane & 15, lr4 = (lane >> 4) * 4;
    const _Float16 inf16 = __builtin_bit_cast(_Float16, (unsigned short)0x7C00);
    #pragma unroll
    for (int jj = 0; jj < 4; jj++) {
        int n = n0 + wn + jj * 16 + l15;
        float bn = bias[n];
        int dirn = n >= 384;
        int col = n - dirn * 384;
        int zcol = (col >= 128) & (col < 256);
        _Float16* Cx = Xt + (long)dirn * T * B_ * 384;
        #pragma unroll
        for (int i = 0; i < 4; i++) {
            int mb = m0 + wm + i * 16 + lr4;     // T-major rows: t = m>>5, b = m&31
            int t = mb >> 5, bb = mb & 31;
            int lrow = wm + i * 16 + lr4;
            #pragma unroll
            for (int q = 0; q < 4; q++) {
                _Float16 v = (_Float16)(acc[i][jj][q] + bn);
                if (zcol && toks[lrow + q] == 0) v = inf16;   // freeze h at masked steps
                Cx[((long)t * B_ + bb + q) * 384 + col] = v;
            }
        }
    }
}

// ---------------- GRU recurrence: 4-way K-split, 512 threads/chain (r14 exact) ----------------
#define D1(A, WU, HU) A = __builtin_amdgcn_fdot2( \
    __builtin_bit_cast(half2v, (WU)), __builtin_bit_cast(half2v, (HU)), A, false);
#define D4(A, W, H) D1(A,(W).x,(H).x) D1(A,(W).y,(H).y) D1(A,(W).z,(H).z) D1(A,(W).w,(H).w)

__global__ __launch_bounds__(512, 1) void k_gru() {
    int blk = blockIdx.x;               // [isQ][dir][b]
    int isQ = blk >> 6, loc = blk & 63, dir = loc >> 5, b = loc & 31;
    const int T = isQ ? Q_ : P_;
    const _Float16* xt = (isQ ? g_xtq : g_xtp) + (long)dir * T * B_ * 384;
    float* outp = isQ ? g_qenc : g_penc;
    int widx = isQ * 2 + dir;
    int tid = threadIdx.x;
    int j = tid >> 2, q = tid & 3;      // col 0..127, k-quarter 0..3
    const uint4* wp = g_whhw + ((long)widx * 512 + tid) * 12;
    uint4 w00 = wp[0], w01 = wp[1], w02 = wp[2],  w03 = wp[3];
    uint4 w10 = wp[4], w11 = wp[5], w12 = wp[6],  w13 = wp[7];
    uint4 w20 = wp[8], w21 = wp[9], w22 = wp[10], w23 = wp[11];
    float bnn = g_biasn[widx][j];
    __shared__ uint hbuf[2][64];        // h as packed f16 (256B), double-buffered
    int t0 = dir ? T - 1 : 0;
    int sdt = dir ? -(B_ * 384) : (B_ * 384);
    int sdo = dir ? -H_ : H_;
    int off = (t0 * B_ + b) * 384 + j;
    int ooff = (b * T + t0) * H_ + dir * HH_ + j;
    float xr = (float)xt[off], xz = (float)xt[off + 128], xn = (float)xt[off + 256];
    uint4 z4 = {0u, 0u, 0u, 0u};
    uint4 h0 = z4, h1 = z4, h2 = z4, h3 = z4;
    float hold = 0.f;
    for (int st = 0; st < T; st++) {
        int offn = off + ((st + 1 < T) ? sdt : 0);
        float nxr = (float)xt[offn], nxz = (float)xt[offn + 128], nxn = (float)xt[offn + 256];
        float ar0 = 0.f, ar1 = 0.f, az0 = 0.f, az1 = 0.f, an0 = 0.f, an1 = 0.f;
        D4(ar0, w00, h0) D4(ar1, w01, h1) D4(ar0, w02, h2) D4(ar1, w03, h3)
        D4(az0, w10, h0) D4(az1, w11, h1) D4(az0, w12, h2) D4(az1, w13, h3)
        D4(an0, w20, h0) D4(an1, w21, h1) D4(an0, w22, h2) D4(an1, w23, h3)
        float ar = ar0 + ar1, az = az0 + az1, an = an0 + an1;
        ar += __shfl_xor(ar, 1); ar += __shfl_xor(ar, 2);
        az += __shfl_xor(az, 1); az += __shfl_xor(az, 2);
        an += __shfl_xor(an, 1); an += __shfl_xor(an, 2);
        // gates (masked steps: xz=+inf -> z=1 -> h frozen exactly)
        float rg = __builtin_amdgcn_rcpf(1.f + __expf(-(ar + xr)));
        float zg = __builtin_amdgcn_rcpf(1.f + __expf(-(az + xz)));
        float ta = __builtin_amdgcn_fmed3f(fmaf(rg, an + bnn, xn), -15.f, 15.f);
        float e2 = __expf(2.f * ta);
        float th = fmaf(-2.f, __builtin_amdgcn_rcpf(e2 + 1.f), 1.f);
        float hv = fmaf(zg, hold - th, th);
        hold = hv;
        if (q == 0) {
            outp[ooff] = hv;                             // fire-and-forget store
            ((_Float16*)hbuf[st & 1])[j] = (_Float16)hv; // 2B h write
        }
        asm volatile("s_waitcnt lgkmcnt(0)\n\ts_barrier" ::: "memory");
        const uint4* hb = (const uint4*)hbuf[st & 1] + q * 4;
        h0 = hb[0]; h1 = hb[1]; h2 = hb[2]; h3 = hb[3];
        off = offn; ooff += sdo;
        xr = nxr; xz = nxz; xn = nxn;
    }
}

// ---------------- fused attention + output heads: wave-per-row, barrier-free ----------------
#define QH 288
__global__ __launch_bounds__(256) void k_attn(const int* pass, const int* ques,
        const float* attn_w, const float* attn_b, const float* start_w,
        const float* start_b, const float* end_w, const float* end_b, float* out) {
    __shared__ _Float16 qsh[64][QH];    // 36,864 B
    __shared__ uint pw3u[4][128];       // per-wave pw3 as f16 pairs
    __shared__ _Float16 w2h[256];
    int b = blockIdx.x >> 4, pblk = blockIdx.x & 15;
    int tid = threadIdx.x, lane = tid & 63, wid = tid >> 6;
    {   // stage qenc (f32 -> f16)
        int q = tid >> 2, hb = (tid & 3) * 64;
        const float* src = g_qenc + ((long)(b * Q_ + q)) * H_ + hb;
        #pragma unroll
        for (int i = 0; i < 16; i++) {
            float4 v = *(const float4*)(src + i * 4);
            half2v a, c;
            a[0] = (_Float16)v.x; a[1] = (_Float16)v.y;
            c[0] = (_Float16)v.z; c[1] = (_Float16)v.w;
            uint2 pk = { __builtin_bit_cast(u32, a), __builtin_bit_cast(u32, c) };
            *(uint2*)&qsh[q][hb + i * 4] = pk;
        }
        if (tid < 128) {
            half2v a;
            a[0] = (_Float16)attn_w[256 + 2 * tid];
            a[1] = (_Float16)attn_w[256 + 2 * tid + 1];
            *(uint*)&w2h[2 * tid] = __builtin_bit_cast(u32, a);
        }
    }
    __syncthreads();                    // only barrier in the kernel
    int qm = ques[b * Q_ + lane] != 0;
    float s2;
    {
        float a0 = 0.f, a1 = 0.f;
        const uint4* qrow = (const uint4*)&qsh[lane][0];
        const uint4* wrow = (const uint4*)w2h;
        #pragma unroll
        for (int i = 0; i < 32; i++) {
            uint4 qv = qrow[i]; uint4 wv = wrow[i];
            D1(a0, qv.x, wv.x) D1(a1, qv.y, wv.y) D1(a0, qv.z, wv.z) D1(a1, qv.w, wv.w)
        }
        s2 = a0 + a1;
    }
    float4 w1 = *(const float4*)(attn_w + 4 * lane);
    float4 w3 = *(const float4*)(attn_w + 512 + 4 * lane);
    float4 sA = *(const float4*)(start_w + 4 * lane);
    float4 sB = *(const float4*)(start_w + 256 + 4 * lane);
    float4 sC = *(const float4*)(start_w + 512 + 4 * lane);
    float4 eA = *(const float4*)(end_w + 4 * lane);
    float4 eB = *(const float4*)(end_w + 256 + 4 * lane);
    float4 eC = *(const float4*)(end_w + 512 + 4 * lane);
    float ab = attn_b[0], sb = start_b[0], ebv = end_b[0];
    uint* mypw = pw3u[wid];
    const uint4* pwrow = (const uint4*)mypw;
    for (int r = 0; r < 8; r++) {
        int p = pblk * 32 + wid * 8 + r;
        long prow = (long)(b * P_ + p);
        int ptok = pass[prow];          // prefetched, used at the end
        float4 pv = *(const float4*)(g_penc + prow * H_ + 4 * lane);
        float s1p = wsum(pv.x * w1.x + pv.y * w1.y + pv.z * w1.z + pv.w * w1.w);
        half2v h01, h23;
        h01[0] = (_Float16)(pv.x * w3.x); h01[1] = (_Float16)(pv.y * w3.y);
        h23[0] = (_Float16)(pv.z * w3.z); h23[1] = (_Float16)(pv.w * w3.w);
        mypw[2 * lane]     = __builtin_bit_cast(u32, h01);
        mypw[2 * lane + 1] = __builtin_bit_cast(u32, h23);
        asm volatile("s_waitcnt lgkmcnt(0)" ::: "memory");  // same-wave LDS visibility
        float c0 = 0.f, c1 = 0.f;
        const uint4* qrow = (const uint4*)&qsh[lane][0];
        #pragma unroll
        for (int i = 0; i < 32; i++) {
            uint4 qv = qrow[i]; uint4 wv = pwrow[i];
            D1(c0, qv.x, wv.x) D1(c1, qv.y, wv.y) D1(c0, qv.z, wv.z) D1(c1, qv.w, wv.w)
        }
        float logit = qm ? (s1p + s2 + c0 + c1 + ab) : NEG;
        float m = wmax(logit);
        float e = __expf(logit - m);
        float ss = wsum(e);
        float prob = e / ss;
        // attw for own h = 4*lane..4*lane+3 (packed f16 accum)
        half2v aw01 = {(_Float16)0.f, (_Float16)0.f}, aw23 = aw01;
        #pragma unroll 8
        for (int q2 = 0; q2 < 64; q2++) {
            float pq = __shfl(prob, q2);
            half2v ph; ph[0] = (_Float16)pq; ph[1] = ph[0];
            uint2 qv = *(const uint2*)&qsh[q2][4 * lane];
            aw01 += __builtin_bit_cast(half2v, qv.x) * ph;
            aw23 += __builtin_bit_cast(half2v, qv.y) * ph;
        }
        float a0 = (float)aw01[0], a1 = (float)aw01[1];
        float a2 = (float)aw23[0], a3 = (float)aw23[1];
        float spv = pv.x * sA.x + a0 * sB.x + pv.x * a0 * sC.x
                  + pv.y * sA.y + a1 * sB.y + pv.y * a1 * sC.y
                  + pv.z * sA.z + a2 * sB.z + pv.z * a2 * sC.z
                  + pv.w * sA.w + a3 * sB.w + pv.w * a3 * sC.w;
        float epv = pv.x * eA.x + a0 * eB.x + pv.x * a0 * eC.x
                  + pv.y * eA.y + a1 * eB.y + pv.y * a1 * eC.y
                  + pv.z * eA.z + a2 * eB.z + pv.z * a2 * eC.z
                  + pv.w * eA.w + a3 * eB.w + pv.w * a3 * eC.w;
        spv = wsum(spv);
        epv = wsum(epv);
        if (lane == 0) {
            int pm = (ptok != 0);
            out[prow]      = pm ? (spv + sb)  : NEG;
            out[BP + prow] = pm ? (epv + ebv) : NEG;
        }
    }
}

// ---------------- log_softmax over P per (batch, start/end) ----------------
__global__ __launch_bounds__(256) void k_lsm(float* out) {
    int b = blockIdx.x >> 1, which = blockIdx.x & 1;
    const float* src = out + which * BP + b * P_;
    int tid = threadIdx.x;
    float v0 = src[tid], v1 = src[tid + 256];
    __shared__ float red[4];
    float m = wmax(fmaxf(v0, v1));
    if ((tid & 63) == 0) red[tid >> 6] = m;
    __syncthreads();
    m = fmaxf(fmaxf(red[0], red[1]), fmaxf(red[2], red[3]));
    __syncthreads();
    float ss = wsum(__expf(v0 - m) + __expf(v1 - m));
    if ((tid & 63) == 0) red[tid >> 6] = ss;
    __syncthreads();
    float lse = m + logf(red[0] + red[1] + red[2] + red[3]);
    float* dst = out + (2 + which) * BP + b * P_;
    dst[tid] = v0 - lse;
    dst[tid + 256] = v1 - lse;
}

extern "C" void kernel_launch(void* const* d_in, const int* in_sizes, int n_in,
                              void* d_out, int out_size, void* d_ws, size_t ws_size,
                              hipStream_t stream) {
    const int* pass = (const int*)d_in[0];
    const int* ques = (const int*)d_in[1];
    const float* emb = (const float*)d_in[2];
    PrepArgs pa;
    const int base[4] = {3, 7, 11, 15};   // p_f, p_b, q_f, q_b blocks of 4 inputs
    for (int i = 0; i < 4; i++) {
        pa.wih[i] = (const float*)d_in[base[i] + 0];
        pa.whh[i] = (const float*)d_in[base[i] + 1];
        pa.bih[i] = (const float*)d_in[base[i] + 2];
        pa.bhh[i] = (const float*)d_in[base[i] + 3];
    }
    const float* attn_w  = (const float*)d_in[19];
    const float* attn_b  = (const float*)d_in[20];
    const float* start_w = (const float*)d_in[21];
    const float* start_b = (const float*)d_in[22];
    const float* end_w   = (const float*)d_in[23];
    const float* end_b   = (const float*)d_in[24];
    float* out = (float*)d_out;

    k_prep <<<dim3(196), dim3(512), 0, stream>>>(pa);
    k_gemm <<<dim3(144, 6), dim3(256), 0, stream>>>(pass, ques, emb);
    k_gru  <<<dim3(128), dim3(512), 0, stream>>>();
    k_attn <<<dim3(B_ * 16), dim3(256), 0, stream>>>(pass, ques, attn_w, attn_b,
                                                     start_w, start_b, end_w, end_b, out);
    k_lsm  <<<dim3(64), dim3(256), 0, stream>>>(out);
}